// Round 1
// baseline (513.707 us; speedup 1.0000x reference)
//
#include <hip/hip_runtime.h>

#define BATCH 8192
#define SEQ 512
#define INND 5
#define HID 64

typedef __attribute__((ext_vector_type(8))) short short8;
typedef __attribute__((ext_vector_type(4))) float f32x4;

__device__ __forceinline__ unsigned short f2bf(float f) {
  union { float f; unsigned u; } v; v.f = f;
  unsigned r = v.u + 0x7FFFu + ((v.u >> 16) & 1u);
  return (unsigned short)(r >> 16);
}
__device__ __forceinline__ float bf2f(unsigned short s) {
  union { unsigned u; float f; } v; v.u = ((unsigned)s) << 16;
  return v.f;
}
__device__ __forceinline__ float sigm(float z) {
  return __builtin_amdgcn_rcpf(1.f + __expf(-z));
}
__device__ __forceinline__ float tanh_(float z) {
  // tanh(z) = 1 - 2/(exp(2z)+1); saturates correctly at +/-1 for large |z|
  return 1.f - 2.f * __builtin_amdgcn_rcpf(1.f + __expf(2.f * z));
}

// One WG (4 waves) owns 16 batch rows. Wave w computes gate-columns
// [16w,16w+16) of each of i,f,g,o via MFMA tiles {w, w+4, w+8, w+12}.
// K is extended: k 0..63 = h, 64..68 = x_t, 69 = 1.0 (bias), 70..95 = 0.
// W_cat fragments live in registers; h/x flow through double-buffered LDS.
__global__ __launch_bounds__(256) void lstm_kernel(
    const float* __restrict__ inputs, const float* __restrict__ W_ih,
    const float* __restrict__ W_hh, const float* __restrict__ b_ih,
    const float* __restrict__ b_hh, const float* __restrict__ fc_w,
    const float* __restrict__ fc_b, float* __restrict__ out) {
  // 104 shorts per row (96 used + pad) -> 208B stride, bank-balanced b128 reads
  __shared__ unsigned short hbuf[2][16][104] __attribute__((aligned(16)));

  const int tid = threadIdx.x;
  const int lane = tid & 63;
  const int w = tid >> 6;        // wave id 0..3
  const int l15 = lane & 15;
  const int kg = lane >> 4;      // k-group 0..3
  const int b0 = blockIdx.x * 16;

  // ---------------- W_cat fragments (registers) ----------------
  // B-frag for tile X, kstep s: lane holds W_cat[col][k], col=64X+16w+l15,
  // k = 32s + 8*kg + j  (j=0..7)
  short8 wf[4][3];
#pragma unroll
  for (int X = 0; X < 4; ++X) {
    const int col = 64 * X + 16 * w + l15;
    const float* wr = W_hh + col * 64;
#pragma unroll
    for (int s = 0; s < 2; ++s) {
      const float* p = wr + 32 * s + 8 * kg;
      short8 v;
#pragma unroll
      for (int j = 0; j < 8; ++j) v[j] = (short)f2bf(p[j]);
      wf[X][s] = v;
    }
    short8 e;
#pragma unroll
    for (int j = 0; j < 8; ++j) e[j] = 0;
    if (kg == 0) {  // k = 64..71
#pragma unroll
      for (int j = 0; j < 5; ++j) e[j] = (short)f2bf(W_ih[col * 5 + j]);
      e[5] = (short)f2bf(b_ih[col] + b_hh[col]);  // k=69: bias (pairs with 1.0)
    }
    wf[X][2] = e;
  }

  // ---------------- x writer lanes ----------------
  const bool writer = (tid < 16 * INND);  // 80 lanes: (row, i)
  const int wrow = tid / INND;
  const int wi = tid - wrow * INND;
  const float* xptr = inputs + (size_t)(b0 + wrow) * (SEQ * INND) + wi;

  // ---------------- LDS init ----------------
  for (int i = tid; i < 2 * 16 * 104; i += 256) ((unsigned short*)hbuf)[i] = 0;
  __syncthreads();
  if (tid < 32) hbuf[tid >> 4][tid & 15][69] = 0x3F80;  // the constant-1 column
  float x_next = 0.f;
  if (writer) {
    hbuf[0][wrow][64 + wi] = f2bf(xptr[0]);  // x at t=0
    x_next = xptr[INND];                     // x at t=1
  }
  __syncthreads();

  // ---------------- recurrence ----------------
  float cst[4] = {0.f, 0.f, 0.f, 0.f};  // c for rows kg*4+q, col 16w+l15
  for (int t = 0; t < SEQ; ++t) {
    const int cur = t & 1, nxt = cur ^ 1;

    // prefetch x(t+2) (2-step pipeline hides HBM/L2 latency)
    float x_n2 = 0.f;
    if (writer && t + 2 < SEQ) x_n2 = xptr[(t + 2) * INND];

    f32x4 acc0 = {0.f, 0.f, 0.f, 0.f};
    f32x4 acc1 = {0.f, 0.f, 0.f, 0.f};
    f32x4 acc2 = {0.f, 0.f, 0.f, 0.f};
    f32x4 acc3 = {0.f, 0.f, 0.f, 0.f};
#pragma unroll
    for (int s = 0; s < 3; ++s) {
      const short8 a = *(const short8*)&hbuf[cur][l15][s * 32 + kg * 8];
      acc0 = __builtin_amdgcn_mfma_f32_16x16x32_bf16(a, wf[0][s], acc0, 0, 0, 0);
      acc1 = __builtin_amdgcn_mfma_f32_16x16x32_bf16(a, wf[1][s], acc1, 0, 0, 0);
      acc2 = __builtin_amdgcn_mfma_f32_16x16x32_bf16(a, wf[2][s], acc2, 0, 0, 0);
      ac3:;
      acc3 = __builtin_amdgcn_mfma_f32_16x16x32_bf16(a, wf[3][s], acc3, 0, 0, 0);
    }

    // gates -> c,h (D layout: reg q -> row kg*4+q, col l15)
    unsigned short hw[4];
#pragma unroll
    for (int q = 0; q < 4; ++q) {
      const float iz = sigm(acc0[q]);
      const float fz = sigm(acc1[q]);
      const float gz = tanh_(acc2[q]);
      const float oz = sigm(acc3[q]);
      const float cq = fz * cst[q] + iz * gz;
      cst[q] = cq;
      hw[q] = f2bf(oz * tanh_(cq));
    }
#pragma unroll
    for (int q = 0; q < 4; ++q)
      hbuf[nxt][kg * 4 + q][w * 16 + l15] = hw[q];
    if (writer && t + 1 < SEQ) hbuf[nxt][wrow][64 + wi] = f2bf(x_next);
    x_next = x_n2;
    __syncthreads();
  }

  // ---------------- epilogue: out = leaky_relu(h @ fc_w^T + fc_b) ----------
  // final h (t=512) is in hbuf[0]
  if (tid < 64) {
    const int row = tid >> 2, seg = tid & 3;
    float sum = 0.f;
#pragma unroll
    for (int j = 0; j < 16; ++j)
      sum += bf2f(hbuf[0][row][seg * 16 + j]) * fc_w[seg * 16 + j];
    sum += __shfl_xor(sum, 1);
    sum += __shfl_xor(sum, 2);
    if (seg == 0) {
      const float p = sum + fc_b[0];
      out[b0 + row] = p > 0.f ? p : 0.01f * p;
    }
  }
}

extern "C" void kernel_launch(void* const* d_in, const int* in_sizes, int n_in,
                              void* d_out, int out_size, void* d_ws, size_t ws_size,
                              hipStream_t stream) {
  const float* inputs = (const float*)d_in[0];
  const float* W_ih = (const float*)d_in[1];
  const float* W_hh = (const float*)d_in[2];
  const float* b_ih = (const float*)d_in[3];
  const float* b_hh = (const float*)d_in[4];
  const float* fc_w = (const float*)d_in[5];
  const float* fc_b = (const float*)d_in[6];
  float* out = (float*)d_out;

  lstm_kernel<<<BATCH / 16, 256, 0, stream>>>(inputs, W_ih, W_hh, b_ih, b_hh,
                                              fc_w, fc_b, out);
}